// Round 13
// baseline (239.351 us; speedup 1.0000x reference)
//
#include <hip/hip_runtime.h>

// NeurTWs R13 = R10 main kernel + node-locality binning.
// R12 falsified latency-bound (2x occupancy -> slower): the gather service
// path (random 64B lines through per-XCD L2) is the bound. feat16 has
// 10.5x/node reuse that random order wastes; bin rows by node>>7 (782 bins,
// 16KB feat slice per bin -> L1/L2-hot) and process in bin order.
// Pipeline: feat->f16 (+zero hist) | hist | scan | scatter perm SoA | main.
// Main = R10 structure (768 persistent blocks, bounds(256,3), wave-private
// LDS, GEMM2 via MFMA) reading pnode/pkey and scatter-storing via prow.
// Fragment layouts (gfx950, verified): A/B: idx=lane&15, k=(lane>>4)*8+j;
// C/D: col=lane&15, row=(lane>>4)*4+reg.

typedef _Float16 half8 __attribute__((ext_vector_type(8)));
typedef float floatx4 __attribute__((ext_vector_type(4)));

#define HSTR 40    // h/pe row stride (f16): 80 B
#define WSTR 104   // wm1t row stride (f16): 208 B
#define GRID_MAIN 768

// ---- helper: fp32->f16 feat copy; block 0 also zeroes the histogram ----
__global__ void feat_to_f16(const float* __restrict__ nf,
                            _Float16* __restrict__ o, int n8,
                            unsigned* __restrict__ hist, int bins) {
    if (blockIdx.x == 0)
        for (int b = threadIdx.x; b < bins; b += 256) hist[b] = 0u;
    for (int t = blockIdx.x * 256 + threadIdx.x; t < n8; t += gridDim.x * 256) {
        const float4* p = (const float4*)nf + (size_t)t * 2;
        const float4 a = p[0], b = p[1];
        half8 h;
        h[0] = (_Float16)a.x; h[1] = (_Float16)a.y;
        h[2] = (_Float16)a.z; h[3] = (_Float16)a.w;
        h[4] = (_Float16)b.x; h[5] = (_Float16)b.y;
        h[6] = (_Float16)b.z; h[7] = (_Float16)b.w;
        *((half8*)o + t) = h;
    }
}

// ---- G1: global histogram of node bins (LDS-first) ----
__global__ __launch_bounds__(256) void g1_hist(
    const int* __restrict__ node_idx, int rows,
    unsigned* __restrict__ hist, int bins, int shift) {
    __shared__ unsigned lh[1024];
    for (int b = threadIdx.x; b < bins; b += 256) lh[b] = 0u;
    __syncthreads();
    for (int r = blockIdx.x * 256 + threadIdx.x; r < rows; r += gridDim.x * 256)
        atomicAdd(&lh[((unsigned)node_idx[r]) >> shift], 1u);
    __syncthreads();
    for (int b = threadIdx.x; b < bins; b += 256)
        if (lh[b]) atomicAdd(&hist[b], lh[b]);
}

// ---- G2: exclusive scan (bins <= 1024) -> cursor = bin start ----
__global__ __launch_bounds__(1024) void g2_scan(
    const unsigned* __restrict__ hist, unsigned* __restrict__ cursor, int bins) {
    __shared__ unsigned s[1024];
    const int t = threadIdx.x;
    const unsigned own = (t < bins) ? hist[t] : 0u;
    s[t] = own;
    __syncthreads();
    #pragma unroll
    for (int off = 1; off < 1024; off <<= 1) {
        unsigned v = (t >= off) ? s[t - off] : 0u;
        __syncthreads();
        s[t] += v;
        __syncthreads();
    }
    if (t < bins) cursor[t] = s[t] - own;   // exclusive prefix
}

// ---- G3: scatter rows into bin-ordered SoA (pnode/pkey/prow) ----
__global__ __launch_bounds__(256) void g3_scatter(
    const int* __restrict__ node_idx, const int* __restrict__ key_idx,
    int rows, unsigned* __restrict__ cursor, int bins, int shift,
    unsigned* __restrict__ pnode, unsigned* __restrict__ pkey,
    unsigned* __restrict__ prow) {
    __shared__ unsigned lh[1024];
    __shared__ unsigned lbase[1024];
    const int t = threadIdx.x;
    const int R0 = blockIdx.x * 4096;
    const int rend = (R0 + 4096 < rows) ? R0 + 4096 : rows;
    for (int b = t; b < bins; b += 256) lh[b] = 0u;
    __syncthreads();
    for (int r = R0 + t; r < rend; r += 256)
        atomicAdd(&lh[((unsigned)node_idx[r]) >> shift], 1u);
    __syncthreads();
    for (int b = t; b < bins; b += 256) {
        const unsigned c = lh[b];
        lbase[b] = c ? atomicAdd(&cursor[b], c) : 0u;
    }
    __syncthreads();
    for (int r = R0 + t; r < rend; r += 256) {
        const unsigned nd = (unsigned)node_idx[r];
        const unsigned b  = nd >> shift;
        const unsigned k  = atomicSub(&lh[b], 1u) - 1u;  // local rank
        const unsigned p  = lbase[b] + k;
        pnode[p] = nd;
        pkey[p]  = (unsigned)key_idx[r];
        prow[p]  = (unsigned)r;
    }
}

__global__ __launch_bounds__(256, 3) void neurtw_r13(
    const float* __restrict__ pos_table,   // [NUM_KEYS, 4]
    const float* __restrict__ node_feat,   // [NUM_NODES, 64] fp32 (fallback)
    const float* __restrict__ W1,          // [4, 32]
    const float* __restrict__ b1,          // [32]
    const float* __restrict__ W2,          // [32, 32]
    const float* __restrict__ b2,          // [32]
    const float* __restrict__ Wm1,         // [96, 64]
    const float* __restrict__ bm1,         // [64]
    const float* __restrict__ Wm2,         // [64, 1]
    const float* __restrict__ bm2,         // [1]
    const unsigned* __restrict__ pnode,    // [rows] (perm or raw node_idx)
    const unsigned* __restrict__ pkey,     // [rows] (perm or raw key_idx)
    const unsigned* __restrict__ prow,     // [rows] orig row ids (or NULL)
    const _Float16* __restrict__ feat16,   // [NUM_NODES, 64] f16 (ws)
    int use_f16, int use_perm,
    float*       __restrict__ out,         // [rows]
    int rows)
{
    __shared__ _Float16 hpe[256 * HSTR];   // 20 KB (h then pe; wave-private)
    __shared__ _Float16 wm1t[64 * WSTR];   // 13 KB  wm1t[n][k] = Wm1[k][n]

    const int tid  = threadIdx.x;
    const int lane = tid & 63;
    const int r0   = (tid >> 6) * 64;
    const int ln   = lane & 15;
    const int q    = lane >> 4;

    // ---------- once per block: stage Wm1^T into LDS ----------
    #pragma unroll
    for (int i = 0; i < 3; ++i) {
        const int task = i * 256 + tid;
        const int n = task & 63, k8 = task >> 6;
        half8 w;
        #pragma unroll
        for (int kk2 = 0; kk2 < 8; ++kk2)
            w[kk2] = (_Float16)Wm1[(k8 * 8 + kk2) * 64 + n];
        *(half8*)(&wm1t[n * WSTR + k8 * 8]) = w;
    }

    // ---------- once per block: per-lane weight/bias fragments ----------
    half8 b_w2[2];
    #pragma unroll
    for (int ct = 0; ct < 2; ++ct)
        #pragma unroll
        for (int j = 0; j < 8; ++j)
            b_w2[ct][j] = (_Float16)W2[(q * 8 + j) * 32 + ct * 16 + ln];
    float b2v[2];
    b2v[0] = b2[ln]; b2v[1] = b2[16 + ln];
    float bm1v[4], wm2v[4];
    #pragma unroll
    for (int ct = 0; ct < 4; ++ct) {
        bm1v[ct] = bm1[ct * 16 + ln];
        wm2v[ct] = Wm2[ct * 16 + ln];
    }
    const float bm2s = bm2[0];

    __syncthreads();   // wm1t staged (the ONLY barrier in the kernel)

    for (int base = blockIdx.x * 256; base < rows; base += GRID_MAIN * 256) {
        // ---- gathers ----
        int ndr[4];
        #pragma unroll
        for (int rt = 0; rt < 4; ++rt)
            ndr[rt] = (int)pnode[base + r0 + rt * 16 + ln];

        half8 fA[4][2];
        if (use_f16) {
            #pragma unroll
            for (int rt = 0; rt < 4; ++rt) {
                const _Float16* fb = feat16 + (size_t)ndr[rt] * 64 + q * 8;
                fA[rt][0] = *(const half8*)(fb);
                fA[rt][1] = *(const half8*)(fb + 32);
            }
        } else {
            #pragma unroll
            for (int rt = 0; rt < 4; ++rt) {
                const float* fb = node_feat + (size_t)ndr[rt] * 64 + q * 8;
                #pragma unroll
                for (int kt = 0; kt < 2; ++kt) {
                    const float4 lo = *(const float4*)(fb + kt * 32);
                    const float4 hi = *(const float4*)(fb + kt * 32 + 4);
                    half8 h;
                    h[0] = (_Float16)lo.x; h[1] = (_Float16)lo.y;
                    h[2] = (_Float16)lo.z; h[3] = (_Float16)lo.w;
                    h[4] = (_Float16)hi.x; h[5] = (_Float16)hi.y;
                    h[6] = (_Float16)hi.z; h[7] = (_Float16)hi.w;
                    fA[rt][kt] = h;
                }
            }
        }

        const int kk = (int)pkey[base + tid];
        const float4 enc = *(const float4*)(pos_table + (size_t)kk * 4);

        // ---- GEMM1 (VALU fp32, uniform weights via s_load) -> h ----
        #pragma unroll
        for (int g = 0; g < 4; ++g) {
            half8 hv;
            #pragma unroll
            for (int j8 = 0; j8 < 8; ++j8) {
                const int j = g * 8 + j8;
                float a = fmaf(enc.w, W1[96 + j],
                          fmaf(enc.z, W1[64 + j],
                          fmaf(enc.y, W1[32 + j],
                          fmaf(enc.x, W1[j], b1[j]))));
                hv[j8] = (_Float16)fmaxf(a, 0.0f);
            }
            *(half8*)(&hpe[tid * HSTR + g * 8]) = hv;
        }
        // wave-private transpose read — no barrier (same wave wrote it)
        half8 a_h[4];
        #pragma unroll
        for (int rt = 0; rt < 4; ++rt)
            a_h[rt] = *(const half8*)(&hpe[(r0 + rt * 16 + ln) * HSTR + q * 8]);

        // ---- GEMM2: 8 MFMA -> pe (C-layout regs) ----
        floatx4 pc[4][2];
        #pragma unroll
        for (int rt = 0; rt < 4; ++rt)
            #pragma unroll
            for (int ct = 0; ct < 2; ++ct) {
                floatx4 c = {0.f, 0.f, 0.f, 0.f};
                pc[rt][ct] = __builtin_amdgcn_mfma_f32_16x16x32_f16(
                    a_h[rt], b_w2[ct], c, 0, 0, 0);
            }

        #pragma unroll
        for (int rt = 0; rt < 4; ++rt)
            #pragma unroll
            for (int ct = 0; ct < 2; ++ct)
                #pragma unroll
                for (int r = 0; r < 4; ++r)
                    hpe[(r0 + rt * 16 + q * 4 + r) * HSTR + ct * 16 + ln] =
                        (_Float16)(pc[rt][ct][r] + b2v[ct]);
        // no barrier: reader below is the same wave

        // ---- GEMM3: 48 MFMA ----
        floatx4 acc[4][4];
        #pragma unroll
        for (int ct = 0; ct < 4; ++ct) {
            const float bb = bm1v[ct];
            #pragma unroll
            for (int rt = 0; rt < 4; ++rt)
                acc[rt][ct] = (floatx4){bb, bb, bb, bb};
        }

        {   // ktile 0: A = pe from LDS
            half8 a_pe[4];
            #pragma unroll
            for (int rt = 0; rt < 4; ++rt)
                a_pe[rt] = *(const half8*)(&hpe[(r0 + rt * 16 + ln) * HSTR + q * 8]);
            half8 b0[4];
            #pragma unroll
            for (int ct = 0; ct < 4; ++ct)
                b0[ct] = *(const half8*)(&wm1t[(ct * 16 + ln) * WSTR + q * 8]);
            #pragma unroll
            for (int rt = 0; rt < 4; ++rt)
                #pragma unroll
                for (int ct = 0; ct < 4; ++ct)
                    acc[rt][ct] = __builtin_amdgcn_mfma_f32_16x16x32_f16(
                        a_pe[rt], b0[ct], acc[rt][ct], 0, 0, 0);
        }

        #pragma unroll
        for (int kt = 0; kt < 2; ++kt) {   // ktiles 1,2: A = feat
            half8 bk[4];
            #pragma unroll
            for (int ct = 0; ct < 4; ++ct)
                bk[ct] = *(const half8*)(&wm1t[(ct * 16 + ln) * WSTR + 32 + kt * 32 + q * 8]);
            #pragma unroll
            for (int rt = 0; rt < 4; ++rt)
                #pragma unroll
                for (int ct = 0; ct < 4; ++ct)
                    acc[rt][ct] = __builtin_amdgcn_mfma_f32_16x16x32_f16(
                        fA[rt][kt], bk[ct], acc[rt][ct], 0, 0, 0);
        }

        // ---- GEMM4: relu + Wm2 dot + butterfly + scatter store ----
        #pragma unroll
        for (int rt = 0; rt < 4; ++rt) {
            #pragma unroll
            for (int r = 0; r < 4; ++r) {
                float p = 0.0f;
                #pragma unroll
                for (int ct = 0; ct < 4; ++ct)
                    p = fmaf(fmaxf(acc[rt][ct][r], 0.0f), wm2v[ct], p);
                p += __shfl_xor(p, 1);
                p += __shfl_xor(p, 2);
                p += __shfl_xor(p, 4);
                p += __shfl_xor(p, 8);
                if (ln == 0) {
                    const int pos = base + r0 + rt * 16 + q * 4 + r;
                    const int orow = use_perm ? (int)prow[pos] : pos;
                    out[orow] = p + bm2s;
                }
            }
        }
    }
}

extern "C" void kernel_launch(void* const* d_in, const int* in_sizes, int n_in,
                              void* d_out, int out_size, void* d_ws, size_t ws_size,
                              hipStream_t stream) {
    const float* pos_table = (const float*)d_in[0];
    const float* node_feat = (const float*)d_in[1];
    const float* W1        = (const float*)d_in[2];
    const float* b1        = (const float*)d_in[3];
    const float* W2        = (const float*)d_in[4];
    const float* b2        = (const float*)d_in[5];
    const float* Wm1       = (const float*)d_in[6];
    const float* bm1       = (const float*)d_in[7];
    const float* Wm2       = (const float*)d_in[8];
    const float* bm2       = (const float*)d_in[9];
    const int*   key_idx   = (const int*)d_in[10];
    const int*   node_idx  = (const int*)d_in[11];
    float* out = (float*)d_out;

    const int rows   = in_sizes[10];               // 1,048,576
    const int nfeat  = in_sizes[1];                // NUM_NODES*64
    const int nnodes = nfeat / 64;                 // 100,000

    int shift = 7;
    while (((nnodes + (1 << shift) - 1) >> shift) > 1024) ++shift;
    const int bins = (nnodes + (1 << shift) - 1) >> shift;   // 782

    // ws layout (16B aligned): feat16 | pnode | pkey | prow | hist | cursor
    size_t off = 0;
    _Float16* feat16 = (_Float16*)((char*)d_ws + off);
    off += ((size_t)nfeat * 2 + 255) & ~(size_t)255;
    unsigned* pnode = (unsigned*)((char*)d_ws + off); off += (size_t)rows * 4;
    unsigned* pkey  = (unsigned*)((char*)d_ws + off); off += (size_t)rows * 4;
    unsigned* prow  = (unsigned*)((char*)d_ws + off); off += (size_t)rows * 4;
    unsigned* hist  = (unsigned*)((char*)d_ws + off); off += (size_t)bins * 4;
    unsigned* cursor= (unsigned*)((char*)d_ws + off); off += (size_t)bins * 4;

    const size_t need_f16  = (size_t)nfeat * 2;
    const size_t need_full = off;
    const int use_f16  = (ws_size >= need_f16) ? 1 : 0;
    const int use_perm = (ws_size >= need_full && use_f16) ? 1 : 0;

    if (use_f16) {
        const int n8 = nfeat / 8;
        feat_to_f16<<<768, 256, 0, stream>>>(node_feat, feat16, n8,
                                             hist, use_perm ? bins : 0);
    }
    if (use_perm) {
        g1_hist<<<256, 256, 0, stream>>>(node_idx, rows, hist, bins, shift);
        g2_scan<<<1, 1024, 0, stream>>>(hist, cursor, bins);
        g3_scatter<<<(rows + 4095) / 4096, 256, 0, stream>>>(
            node_idx, key_idx, rows, cursor, bins, shift, pnode, pkey, prow);
    }

    const unsigned* pn = use_perm ? pnode : (const unsigned*)node_idx;
    const unsigned* pk = use_perm ? pkey  : (const unsigned*)key_idx;
    const unsigned* pr = use_perm ? prow  : (const unsigned*)node_idx; // unused if !use_perm

    neurtw_r13<<<GRID_MAIN, 256, 0, stream>>>(
        pos_table, node_feat, W1, b1, W2, b2, Wm1, bm1, Wm2, bm2,
        pn, pk, pr, feat16, use_f16, use_perm, out, rows);
}

// Round 14
// 160.570 us; speedup vs baseline: 1.4906x; 1.4906x over previous
//
#include <hip/hip_runtime.h>

// NeurTWs R14 = R10 (best: 62us steady, clean counters) + f16 pos_table.
// Five attack angles failed to beat R10: scheduling (R10/R11 neutral),
// occupancy up (R12 slower), reg-structure (R7/R8 spill), node binning
// (R13: FETCH -24MB but scatter-store +30MB, slower). Binding constraint:
// beyond-L2 random-line gather service. Remaining lever: shrink the gather
// footprint. pos_table fp32 16MB -> f16 8MB: doubles keys/line (8/64B),
// halves per-XCD L2 footprint -> fewer beyond-L2 line fills, zero extra
// per-iter work. enc in [0,1): f16 err 2^-11 -> |dz|~1e-4, negligible.
// Main kernel structure, launch config byte-for-byte R10:
// 768 persistent blocks, bounds(256,3), wave-private LDS (one barrier),
// GEMM2 via MFMA, GEMM4 shuffle reduce.
// Fragment layouts (gfx950, verified): A/B: idx=lane&15, k=(lane>>4)*8+j;
// C/D: col=lane&15, row=(lane>>4)*4+reg.

typedef _Float16 half8 __attribute__((ext_vector_type(8)));
typedef _Float16 half4v __attribute__((ext_vector_type(4)));
typedef float floatx4 __attribute__((ext_vector_type(4)));

#define HSTR 40    // h/pe row stride (f16): 80 B
#define WSTR 104   // wm1t row stride (f16): 208 B
#define GRID_MAIN 768

// ---- helper: fp32->f16 copies for node_feat AND pos_table ----
__global__ void tables_to_f16(const float* __restrict__ nf, _Float16* __restrict__ of,
                              int n8f,
                              const float* __restrict__ pt, _Float16* __restrict__ op,
                              int n8p) {
    for (int t = blockIdx.x * 256 + threadIdx.x; t < n8f + n8p; t += gridDim.x * 256) {
        const int is_p = (t >= n8f);
        const float4* p = (const float4*)(is_p ? pt : nf) + (size_t)(is_p ? t - n8f : t) * 2;
        const float4 a = p[0], b = p[1];
        half8 h;
        h[0] = (_Float16)a.x; h[1] = (_Float16)a.y;
        h[2] = (_Float16)a.z; h[3] = (_Float16)a.w;
        h[4] = (_Float16)b.x; h[5] = (_Float16)b.y;
        h[6] = (_Float16)b.z; h[7] = (_Float16)b.w;
        *((half8*)(is_p ? op : of) + (is_p ? t - n8f : t)) = h;
    }
}

__global__ __launch_bounds__(256, 3) void neurtw_r14(
    const float* __restrict__ pos_table,   // [NUM_KEYS, 4] fp32 (fallback)
    const float* __restrict__ node_feat,   // [NUM_NODES, 64] fp32 (fallback)
    const float* __restrict__ W1,          // [4, 32]
    const float* __restrict__ b1,          // [32]
    const float* __restrict__ W2,          // [32, 32]
    const float* __restrict__ b2,          // [32]
    const float* __restrict__ Wm1,         // [96, 64]
    const float* __restrict__ bm1,         // [64]
    const float* __restrict__ Wm2,         // [64, 1]
    const float* __restrict__ bm2,         // [1]
    const int*   __restrict__ key_idx,     // [rows]
    const int*   __restrict__ node_idx,    // [rows]
    const _Float16* __restrict__ feat16,   // [NUM_NODES, 64] f16 (ws)
    const _Float16* __restrict__ pos16,    // [NUM_KEYS, 4]  f16 (ws)
    int use_f16,
    float*       __restrict__ out,         // [rows]
    int rows)
{
    __shared__ _Float16 hpe[256 * HSTR];   // 20 KB (h then pe; wave-private)
    __shared__ _Float16 wm1t[64 * WSTR];   // 13 KB  wm1t[n][k] = Wm1[k][n]

    const int tid  = threadIdx.x;
    const int lane = tid & 63;
    const int r0   = (tid >> 6) * 64;
    const int ln   = lane & 15;
    const int q    = lane >> 4;

    // ---------- once per block: stage Wm1^T into LDS ----------
    #pragma unroll
    for (int i = 0; i < 3; ++i) {
        const int task = i * 256 + tid;
        const int n = task & 63, k8 = task >> 6;
        half8 w;
        #pragma unroll
        for (int kk2 = 0; kk2 < 8; ++kk2)
            w[kk2] = (_Float16)Wm1[(k8 * 8 + kk2) * 64 + n];
        *(half8*)(&wm1t[n * WSTR + k8 * 8]) = w;
    }

    // ---------- once per block: per-lane weight/bias fragments ----------
    half8 b_w2[2];
    #pragma unroll
    for (int ct = 0; ct < 2; ++ct)
        #pragma unroll
        for (int j = 0; j < 8; ++j)
            b_w2[ct][j] = (_Float16)W2[(q * 8 + j) * 32 + ct * 16 + ln];
    float b2v[2];
    b2v[0] = b2[ln]; b2v[1] = b2[16 + ln];
    float bm1v[4], wm2v[4];
    #pragma unroll
    for (int ct = 0; ct < 4; ++ct) {
        bm1v[ct] = bm1[ct * 16 + ln];
        wm2v[ct] = Wm2[ct * 16 + ln];
    }
    const float bm2s = bm2[0];

    __syncthreads();   // wm1t staged (the ONLY barrier in the kernel)

    for (int base = blockIdx.x * 256; base < rows; base += GRID_MAIN * 256) {
        const int row = base + tid;

        // ---- issue all global loads upfront ----
        int ndr[4];
        #pragma unroll
        for (int rt = 0; rt < 4; ++rt)
            ndr[rt] = node_idx[base + r0 + rt * 16 + ln];

        half8 fA[4][2];                    // feat A-fragments
        float e0, e1, e2, e3;
        const int kk = key_idx[row];
        if (use_f16) {
            #pragma unroll
            for (int rt = 0; rt < 4; ++rt) {
                const _Float16* fb = feat16 + (size_t)ndr[rt] * 64 + q * 8;
                fA[rt][0] = *(const half8*)(fb);
                fA[rt][1] = *(const half8*)(fb + 32);
            }
            const half4v e4 = *(const half4v*)(pos16 + (size_t)kk * 4);
            e0 = (float)e4[0]; e1 = (float)e4[1];
            e2 = (float)e4[2]; e3 = (float)e4[3];
        } else {
            #pragma unroll
            for (int rt = 0; rt < 4; ++rt) {
                const float* fb = node_feat + (size_t)ndr[rt] * 64 + q * 8;
                #pragma unroll
                for (int kt = 0; kt < 2; ++kt) {
                    const float4 lo = *(const float4*)(fb + kt * 32);
                    const float4 hi = *(const float4*)(fb + kt * 32 + 4);
                    half8 h;
                    h[0] = (_Float16)lo.x; h[1] = (_Float16)lo.y;
                    h[2] = (_Float16)lo.z; h[3] = (_Float16)lo.w;
                    h[4] = (_Float16)hi.x; h[5] = (_Float16)hi.y;
                    h[6] = (_Float16)hi.z; h[7] = (_Float16)hi.w;
                    fA[rt][kt] = h;
                }
            }
            const float4 enc = *(const float4*)(pos_table + (size_t)kk * 4);
            e0 = enc.x; e1 = enc.y; e2 = enc.z; e3 = enc.w;
        }

        // ---- GEMM1 (VALU fp32, uniform weights via s_load) -> h ----
        #pragma unroll
        for (int g = 0; g < 4; ++g) {
            half8 hv;
            #pragma unroll
            for (int j8 = 0; j8 < 8; ++j8) {
                const int j = g * 8 + j8;
                float a = fmaf(e3, W1[96 + j],
                          fmaf(e2, W1[64 + j],
                          fmaf(e1, W1[32 + j],
                          fmaf(e0, W1[j], b1[j]))));
                hv[j8] = (_Float16)fmaxf(a, 0.0f);
            }
            *(half8*)(&hpe[tid * HSTR + g * 8]) = hv;
        }
        // wave-private transpose read — no barrier (same wave wrote it)
        half8 a_h[4];
        #pragma unroll
        for (int rt = 0; rt < 4; ++rt)
            a_h[rt] = *(const half8*)(&hpe[(r0 + rt * 16 + ln) * HSTR + q * 8]);

        // ---- GEMM2: 8 MFMA -> pe (C-layout regs) ----
        floatx4 pc[4][2];
        #pragma unroll
        for (int rt = 0; rt < 4; ++rt)
            #pragma unroll
            for (int ct = 0; ct < 2; ++ct) {
                floatx4 c = {0.f, 0.f, 0.f, 0.f};
                pc[rt][ct] = __builtin_amdgcn_mfma_f32_16x16x32_f16(
                    a_h[rt], b_w2[ct], c, 0, 0, 0);
            }

        // write pe into the SAME buffer (h consumed; own wave's slice only)
        #pragma unroll
        for (int rt = 0; rt < 4; ++rt)
            #pragma unroll
            for (int ct = 0; ct < 2; ++ct)
                #pragma unroll
                for (int r = 0; r < 4; ++r)
                    hpe[(r0 + rt * 16 + q * 4 + r) * HSTR + ct * 16 + ln] =
                        (_Float16)(pc[rt][ct][r] + b2v[ct]);
        // no barrier: reader below is the same wave

        // ---- GEMM3: 48 MFMA ----
        floatx4 acc[4][4];
        #pragma unroll
        for (int ct = 0; ct < 4; ++ct) {
            const float bb = bm1v[ct];
            #pragma unroll
            for (int rt = 0; rt < 4; ++rt)
                acc[rt][ct] = (floatx4){bb, bb, bb, bb};
        }

        {   // ktile 0: A = pe from LDS
            half8 a_pe[4];
            #pragma unroll
            for (int rt = 0; rt < 4; ++rt)
                a_pe[rt] = *(const half8*)(&hpe[(r0 + rt * 16 + ln) * HSTR + q * 8]);
            half8 b0[4];
            #pragma unroll
            for (int ct = 0; ct < 4; ++ct)
                b0[ct] = *(const half8*)(&wm1t[(ct * 16 + ln) * WSTR + q * 8]);
            #pragma unroll
            for (int rt = 0; rt < 4; ++rt)
                #pragma unroll
                for (int ct = 0; ct < 4; ++ct)
                    acc[rt][ct] = __builtin_amdgcn_mfma_f32_16x16x32_f16(
                        a_pe[rt], b0[ct], acc[rt][ct], 0, 0, 0);
        }

        #pragma unroll
        for (int kt = 0; kt < 2; ++kt) {   // ktiles 1,2: A = feat
            half8 bk[4];
            #pragma unroll
            for (int ct = 0; ct < 4; ++ct)
                bk[ct] = *(const half8*)(&wm1t[(ct * 16 + ln) * WSTR + 32 + kt * 32 + q * 8]);
            #pragma unroll
            for (int rt = 0; rt < 4; ++rt)
                #pragma unroll
                for (int ct = 0; ct < 4; ++ct)
                    acc[rt][ct] = __builtin_amdgcn_mfma_f32_16x16x32_f16(
                        fA[rt][kt], bk[ct], acc[rt][ct], 0, 0, 0);
        }

        // ---- GEMM4: relu + Wm2 dot + 4-step butterfly + store ----
        #pragma unroll
        for (int rt = 0; rt < 4; ++rt) {
            #pragma unroll
            for (int r = 0; r < 4; ++r) {
                float p = 0.0f;
                #pragma unroll
                for (int ct = 0; ct < 4; ++ct)
                    p = fmaf(fmaxf(acc[rt][ct][r], 0.0f), wm2v[ct], p);
                p += __shfl_xor(p, 1);
                p += __shfl_xor(p, 2);
                p += __shfl_xor(p, 4);
                p += __shfl_xor(p, 8);
                if (ln == 0)
                    out[base + r0 + rt * 16 + q * 4 + r] = p + bm2s;
            }
        }
    }
}

extern "C" void kernel_launch(void* const* d_in, const int* in_sizes, int n_in,
                              void* d_out, int out_size, void* d_ws, size_t ws_size,
                              hipStream_t stream) {
    const float* pos_table = (const float*)d_in[0];
    const float* node_feat = (const float*)d_in[1];
    const float* W1        = (const float*)d_in[2];
    const float* b1        = (const float*)d_in[3];
    const float* W2        = (const float*)d_in[4];
    const float* b2        = (const float*)d_in[5];
    const float* Wm1       = (const float*)d_in[6];
    const float* bm1       = (const float*)d_in[7];
    const float* Wm2       = (const float*)d_in[8];
    const float* bm2       = (const float*)d_in[9];
    const int*   key_idx   = (const int*)d_in[10];
    const int*   node_idx  = (const int*)d_in[11];
    float* out = (float*)d_out;

    const int rows  = in_sizes[10];                // 1,048,576
    const int nfeat = in_sizes[1];                 // NUM_NODES*64
    const int npos  = in_sizes[0];                 // NUM_KEYS*4

    // ws layout: feat16 | pos16 (both 16B-aligned sizes)
    _Float16* feat16 = (_Float16*)d_ws;
    _Float16* pos16  = (_Float16*)((char*)d_ws + (((size_t)nfeat * 2 + 255) & ~(size_t)255));
    const size_t need = (((size_t)nfeat * 2 + 255) & ~(size_t)255) + (size_t)npos * 2;
    const int use_f16 = (ws_size >= need) ? 1 : 0;

    if (use_f16) {
        tables_to_f16<<<768, 256, 0, stream>>>(node_feat, feat16, nfeat / 8,
                                               pos_table, pos16, npos / 8);
    }

    neurtw_r14<<<GRID_MAIN, 256, 0, stream>>>(
        pos_table, node_feat, W1, b1, W2, b2, Wm1, bm1, Wm2, bm2,
        key_idx, node_idx, feat16, pos16, use_f16, out, rows);
}